// Round 9
// baseline (645.141 us; speedup 1.0000x reference)
//
#include <hip/hip_runtime.h>
#include <stdint.h>

// ---------------------------------------------------------------------------
// LSTM pointer-generator decoder step, B=128 TK=400 NK=50 H=E=256 V=50000.
// Round 15: R14's k_scores_f REGRESSED (47us vs <40; half the ILP, half the
// TLP, 3 extra barriers; A-traffic saving was L3-absorbed). Revert to the
// R13 partial structure. New lever: ~200us of the 470 is inter-launch gaps
// (sum of kernels ~255us) -> collapse 18 launches to 10:
//   k_prep     = W2-tc + Whd/Wn-tc + enc/encn-cvt + k_x  (all input-only)
//   k_scores_all = doc + node scores in one grid (450,4), runtime select
//   k_fmax_cd  = fmax + cd (both depend only on a)
//   k_ant_o1   = ant + o1 (both depend on node1)
//   k_vwrite_sc = vwrite + per-chunk pointer scatter (intra-block ordering)
// Math identical to R13's passing version -> absmax unchanged.
// ---------------------------------------------------------------------------

typedef unsigned short u16;
typedef unsigned int   u32;

#define Bv  128
#define TKv 400
#define NKv 50
#define Hv  256
#define Vv  50000
#define VPAD 50176   // 50000 padded to multiple of 128
#define NSv 16
#define CHUNKv 3136  // VPAD / NSv
#define MDOC (Bv * TKv)   // 51200
#define MNODE (Bv * NKv)  // 6400
#define NBLK (VPAD / 64)  // 784 logits col-blocks

// k_prep block ranges
#define NB_TCW2 ((VPAD / 32) * 8)          // 12544
#define NB_PAIR 128                        // 2 x (8x8)
#define NB_CVT  2148                       // 2048 enc + 100 encn
#define NB_KX   (Bv * 4)                   // 512
#define NB_PREP (NB_TCW2 + NB_PAIR + NB_CVT + NB_KX)

typedef __attribute__((ext_vector_type(8))) short bf16x8;
typedef __attribute__((ext_vector_type(4))) float f32x4;

// ---- module-global workspace (no d_ws dependency) -------------------------
__device__ float g_x[32768];      // x = cat @ Wx + bx
__device__ float g_xp[4 * 32768]; // x K-partials
__device__ float g_gates[131072]; // LSTM gates [B,4H]
__device__ float g_h[32768];      // h_new
__device__ float g_c[32768];      // c_new
__device__ float g_sdp[2 * 32768];// s_hat@Wsd partials (no bias)
__device__ float g_sfp[2 * 32768];// s_hat@Wsf partials (no bias)
__device__ float g_ep[4 * MDOC];  // doc score partials (4 col-chunks)
__device__ float g_enp[4 * MNODE];// node score partials
__device__ float g_a[51200];      // doc attention a
__device__ float g_cd[32768];     // c_d
__device__ float g_cdp[8 * 32768];// c_d t-split partials (8 chunks of 50)
__device__ float g_cg[32768];     // c_g
__device__ float g_cg2[32768];    // c_g2
__device__ float g_pg[128];       // p_gen
__device__ float g_ans[MNODE];    // node attention an
__device__ float g_inv4[128];     // 1/S4 for a_n2t
__device__ float g_fl[MNODE];     // unnormalized flow
__device__ float g_nrs[MNODE];    // n2t row sums
__device__ float g_o1[32768];     // out1 (f32)
__device__ __attribute__((aligned(16))) u16 g_o1b[32768]; // out1 bf16
__device__ float g_vpp[(size_t)2 * Bv * NBLK]; // per-(row,blk) (max,sum)
__device__ float g_logits[6400000];        // f32 logits (25.6 MB)
__device__ u16   g_Wdt[256 * 256];         // Whd^T bf16 [n][k]
__device__ u16   g_Wnt[256 * 256];         // Wn^T  bf16 [n][k]
__device__ u16   g_W2t[(size_t)VPAD * 256];// W2^T  bf16 [v][k] (25.7 MB)
__device__ u16   g_encb[(size_t)Bv * TKv * 256]; // enc bf16 (26.2 MB)
__device__ u16   g_encnb[(size_t)Bv * NKv * 256];// encn bf16 (3.3 MB)

__device__ __forceinline__ float sigm(float x) { return 1.f / (1.f + expf(-x)); }

__device__ __forceinline__ u16 f2bf(float f) {
    u32 u = __float_as_uint(f);
    return (u16)((u + 0x7fffu + ((u >> 16) & 1u)) >> 16);  // RNE
}

__device__ __forceinline__ bf16x8 cvt8(const float* __restrict__ p) {
    const float4 a = *(const float4*)p;
    const float4 b = *(const float4*)(p + 4);
    bf16x8 r;
    r[0] = (short)f2bf(a.x); r[1] = (short)f2bf(a.y);
    r[2] = (short)f2bf(a.z); r[3] = (short)f2bf(a.w);
    r[4] = (short)f2bf(b.x); r[5] = (short)f2bf(b.y);
    r[6] = (short)f2bf(b.z); r[7] = (short)f2bf(b.w);
    return r;
}

// tanh via exp; clamp so exp never overflows (tanh saturated anyway)
__device__ __forceinline__ float fast_tanh(float x) {
    x = fminf(fmaxf(x, -15.f), 15.f);
    float e = __expf(2.f * x);
    return (e - 1.f) / (e + 1.f);
}

// online (max,sum) merge: (m1,s1) <- (m1,s1) U (m2,s2)
__device__ __forceinline__ void ms_merge(float& m1, float& s1, float m2, float s2) {
    float M = fmaxf(m1, m2);
    s1 = s1 * expf(m1 - M) + s2 * expf(m2 - M);
    m1 = M;
}

// ---------------------------------------------------------------------------
// K0 (fused prep): all input-only preprocessing in ONE launch.
//   [0, NB_TCW2)              : W2 [256][50000] -> W2^T bf16 [VPAD][256]
//   [NB_TCW2, +NB_PAIR)       : Whd / Wn 256x256 transpose-casts
//   [.., +NB_CVT)             : enc / encn streaming f32->bf16
//   [.., +NB_KX)              : x K-partials (B,4)
// ---------------------------------------------------------------------------
__global__ __launch_bounds__(256) void k_prep(
    const float* __restrict__ Whd, const float* __restrict__ Wn,
    const float* __restrict__ W2,
    const float* __restrict__ enc, const float* __restrict__ encn,
    const int* __restrict__ y,
    const float* __restrict__ ctd, const float* __restrict__ ctg,
    const float* __restrict__ ctg2, const float* __restrict__ emb,
    const float* __restrict__ Wx)
{
    __shared__ float tile[32][33];
    const int tid = threadIdx.x;
    int bid = blockIdx.x;

    if (bid < NB_TCW2) {
        // ---- W2 transpose-cast ----
        const int n0 = (bid % (VPAD / 32)) * 32, k0 = (bid / (VPAD / 32)) * 32;
        const int tx = tid & 31, ty = tid >> 5;
        #pragma unroll
        for (int i = 0; i < 32; i += 8) {
            int k = k0 + ty + i, n = n0 + tx;
            tile[ty + i][tx] = (n < Vv) ? W2[(size_t)k * Vv + n] : 0.f;
        }
        __syncthreads();
        #pragma unroll
        for (int i = 0; i < 32; i += 8) {
            int n = n0 + ty + i, k = k0 + tx;
            g_W2t[(size_t)n * 256 + k] = f2bf(tile[tx][ty + i]);
        }
        return;
    }
    bid -= NB_TCW2;
    if (bid < NB_PAIR) {
        // ---- Whd / Wn transpose-cast ----
        const int z = bid >> 6, rem = bid & 63;
        const float* src = z ? Wn : Whd;
        u16* dst = z ? g_Wnt : g_Wdt;
        const int n0 = (rem & 7) * 32, k0 = (rem >> 3) * 32;
        const int tx = tid & 31, ty = tid >> 5;
        #pragma unroll
        for (int i = 0; i < 32; i += 8)
            tile[ty + i][tx] = src[(size_t)(k0 + ty + i) * 256 + n0 + tx];
        __syncthreads();
        #pragma unroll
        for (int i = 0; i < 32; i += 8)
            dst[(size_t)(n0 + ty + i) * 256 + k0 + tx] = f2bf(tile[tx][ty + i]);
        return;
    }
    bid -= NB_PAIR;
    if (bid < NB_CVT) {
        // ---- enc / encn f32 -> bf16 ----
        if (bid < 2048) {
            const int n8 = Bv * TKv * 256 / 8;
            int i = bid * 256 + tid;
            for (; i < n8; i += 2048 * 256)
                *(bf16x8*)(g_encb + (size_t)i * 8) = cvt8(enc + (size_t)i * 8);
        } else {
            const int n8 = Bv * NKv * 256 / 8;
            int i = (bid - 2048) * 256 + tid;
            for (; i < n8; i += 100 * 256)
                *(bf16x8*)(g_encnb + (size_t)i * 8) = cvt8(encn + (size_t)i * 8);
        }
        return;
    }
    bid -= NB_CVT;
    {
        // ---- x K-partials ----
        const int b = bid >> 2, ks = bid & 3, j = tid;
        float* cs = &tile[0][0];
        float v;
        if      (ks == 0) v = ctd [b * 256 + j];
        else if (ks == 1) v = ctg [b * 256 + j];
        else if (ks == 2) v = ctg2[b * 256 + j];
        else              v = emb[(size_t)y[b] * 256 + j];
        cs[j] = v;
        __syncthreads();

        float acc = 0.f;
        const float* w = Wx + (size_t)(ks * 256) * 256 + j;
        #pragma unroll 8
        for (int k = 0; k < 256; k++) acc += cs[k] * w[(size_t)k * 256];
        g_xp[ks * 32768 + b * 256 + j] = acc;
    }
}

// ---------------------------------------------------------------------------
// K1b: gates = x@Wi + h@Wh + bi + bh. grid (B, 4 col-chunks).
// ---------------------------------------------------------------------------
__global__ __launch_bounds__(256) void k_gates(
    const float* __restrict__ h_prev,
    const float* __restrict__ Wi, const float* __restrict__ Wh,
    const float* __restrict__ bi, const float* __restrict__ bh,
    const float* __restrict__ bx)
{
    const int b = blockIdx.x, cc = blockIdx.y, j = threadIdx.x;
    __shared__ float xs[256], hs[256];

    float xv = bx[j] + g_xp[b * 256 + j] + g_xp[32768 + b * 256 + j]
             + g_xp[65536 + b * 256 + j] + g_xp[98304 + b * 256 + j];
    xs[j] = xv;
    if (cc == 0) g_x[b * 256 + j] = xv;
    hs[j] = h_prev[b * 256 + j];
    __syncthreads();

    const int col = cc * 256 + j;
    float acc = bi[col] + bh[col];
    const float* wi = Wi + col;
    const float* wh = Wh + col;
    #pragma unroll 8
    for (int k = 0; k < 256; k++)
        acc += xs[k] * wi[(size_t)k * 1024] + hs[k] * wh[(size_t)k * 1024];
    g_gates[b * 1024 + col] = acc;
}

// ---------------------------------------------------------------------------
// K1c: LSTM elementwise + sd/sf K-partials. grid (B, 2).
// ---------------------------------------------------------------------------
__global__ __launch_bounds__(256) void k_cellsd(
    const float* __restrict__ c_prev,
    const float* __restrict__ Wsd, const float* __restrict__ Wsf,
    float* __restrict__ out_h, float* __restrict__ out_c)
{
    const int b = blockIdx.x, ks = blockIdx.y, j = threadIdx.x;
    __shared__ float sh[256];

    const float* gb = g_gates + b * 1024;
    float gi_ = gb[j], gf_ = gb[256 + j], gg_ = gb[512 + j], go_ = gb[768 + j];
    float cp = c_prev[b * 256 + j];
    float cn = sigm(gf_) * cp + sigm(gi_) * tanhf(gg_);
    float hn = sigm(go_) * tanhf(cn);
    if (ks == 0) {
        g_h[b * 256 + j] = hn;  g_c[b * 256 + j] = cn;
        out_h[b * 256 + j] = hn; out_c[b * 256 + j] = cn;
    }
    sh[j] = (ks == 0) ? hn : cn;   // s_hat rows [0,256) = h, [256,512) = c
    __syncthreads();

    float asd = 0.f, asf = 0.f;
    const float* wd = Wsd + (size_t)(ks * 256) * 256 + j;
    const float* wf = Wsf + (size_t)(ks * 256) * 256 + j;
    #pragma unroll 8
    for (int k = 0; k < 256; k++) {
        float sv = sh[k];
        asd += sv * wd[(size_t)k * 256];
        asf += sv * wf[(size_t)k * 256];
    }
    g_sdp[ks * 32768 + b * 256 + j] = asd;
    g_sfp[ks * 32768 + b * 256 + j] = asf;
}

// ---------------------------------------------------------------------------
// K2 (MFMA): doc + node score e-PARTIALS in ONE launch. grid (450, 4):
// blockIdx.x < 400 -> doc rows, else node rows. LDS-staged 64-col W chunk
// ([64][264] pad -> 2-way conflicts only), wave = 2 M-tiles x 4 N-tiles,
// A double-buffered from global. R13-proven structure, runtime selection.
// ---------------------------------------------------------------------------
__global__ __launch_bounds__(256) void k_scores_all(
    const float* __restrict__ bd,  const float* __restrict__ bfv,
    const float* __restrict__ cov, const float* __restrict__ wcdw,
    const float* __restrict__ vd,  const float* __restrict__ vf)
{
    const int tid = threadIdx.x;
    const int lane = tid & 63, w = tid >> 6;
    const int nlow = lane & 15, quad = lane >> 4;
    const int c0 = blockIdx.y * 64;

    const bool isdoc = blockIdx.x < (MDOC / 128);
    const int bx = isdoc ? blockIdx.x : blockIdx.x - MDOC / 128;
    const int R = isdoc ? TKv : NKv;
    const int Mtot = isdoc ? MDOC : MNODE;
    const u16* srcb = isdoc ? g_encb : g_encnb;
    const u16* Wt   = isdoc ? g_Wdt : g_Wnt;
    const float* addv0 = isdoc ? g_sdp : g_sfp;
    const float* addv1 = isdoc ? g_sdp + 32768 : g_sfp + 32768;
    const float* abias = isdoc ? bd : bfv;
    const float* covp  = isdoc ? cov : nullptr;
    const float* wcw   = isdoc ? wcdw : nullptr;
    const float* vv    = isdoc ? vd : vf;
    float* eout        = isdoc ? g_ep : g_enp;

    __shared__ u16 Bs[64][264];
    {
        const u16* wsrc = Wt + (size_t)c0 * 256;
        #pragma unroll
        for (int j = 0; j < 8; j++) {
            int chunk = tid + j * 256;
            int row = chunk >> 5, c16 = chunk & 31;
            *(bf16x8*)(&Bs[row][c16 * 8]) =
                *(const bf16x8*)(wsrc + row * 256 + c16 * 8);
        }
    }
    __syncthreads();

    const int rowbase = bx * 128 + w * 32;
    const u16* a0 = srcb + (size_t)(rowbase + nlow) * 256 + quad * 8;
    const u16* a1 = a0 + 16 * 256;

    const f32x4 zf = {0.f, 0.f, 0.f, 0.f};
    f32x4 acc[2][4];
    #pragma unroll
    for (int mi = 0; mi < 2; mi++)
        #pragma unroll
        for (int ni = 0; ni < 4; ni++) acc[mi][ni] = zf;

    bf16x8 af0 = *(const bf16x8*)(a0);
    bf16x8 af1 = *(const bf16x8*)(a1);
    for (int k0 = 0; k0 < 256; k0 += 32) {
        const int kn = (k0 + 32) & 255;   // wrap: last iter re-reads k=0 (discarded)
        bf16x8 nf0 = *(const bf16x8*)(a0 + kn);
        bf16x8 nf1 = *(const bf16x8*)(a1 + kn);
        bf16x8 bf[4];
        #pragma unroll
        for (int ni = 0; ni < 4; ni++)
            bf[ni] = *(const bf16x8*)(&Bs[ni * 16 + nlow][k0 + quad * 8]);
        #pragma unroll
        for (int ni = 0; ni < 4; ni++) {
            acc[0][ni] = __builtin_amdgcn_mfma_f32_16x16x32_bf16(af0, bf[ni], acc[0][ni], 0, 0, 0);
            acc[1][ni] = __builtin_amdgcn_mfma_f32_16x16x32_bf16(af1, bf[ni], acc[1][ni], 0, 0, 0);
        }
        af0 = nf0; af1 = nf1;
    }

    // epilogue: row = rowbase + mi*16 + quad*4 + r, col = c0 + ni*16 + nlow
    #pragma unroll
    for (int mi = 0; mi < 2; mi++) {
        float covt[4]; int bidx[4];
        #pragma unroll
        for (int r = 0; r < 4; r++) {
            int row = rowbase + mi * 16 + quad * 4 + r;
            covt[r] = covp ? covp[row] : 0.f;
            bidx[r] = row / R;
        }
        float s4[4] = {0.f, 0.f, 0.f, 0.f};
        #pragma unroll
        for (int ni = 0; ni < 4; ni++) {
            int col = c0 + ni * 16 + nlow;
            float vvc = vv[col];
            float ab  = abias[col];
            float wcc = wcw ? wcw[col] : 0.f;
            #pragma unroll
            for (int r = 0; r < 4; r++) {
                float adc = addv0[bidx[r] * 256 + col] + addv1[bidx[r] * 256 + col] + ab;
                s4[r] += vvc * fast_tanh(acc[mi][ni][r] + adc + covt[r] * wcc);
            }
        }
        #pragma unroll
        for (int r = 0; r < 4; r++) {
            float s = s4[r];
            s += __shfl_xor(s, 1, 64);
            s += __shfl_xor(s, 2, 64);
            s += __shfl_xor(s, 4, 64);
            s += __shfl_xor(s, 8, 64);
            int row = rowbase + mi * 16 + quad * 4 + r;
            if (nlow == 0)
                eout[(size_t)blockIdx.y * Mtot + row] = s;
        }
    }
}

// ---------------------------------------------------------------------------
// K3: doc softmax (+mask renorm): sums the 4 e-partials, a, coverage_next.
// ---------------------------------------------------------------------------
__global__ __launch_bounds__(256) void k_doc(
    const float* __restrict__ mask,
    const float* __restrict__ cov,
    float* __restrict__ out_a, float* __restrict__ out_cov)
{
    const int b = blockIdx.x, tid = threadIdx.x;
    __shared__ float red[256];

    float e0 = 0.f, e1s = 0.f;
    #pragma unroll
    for (int ch = 0; ch < 4; ch++) {
        e0 += g_ep[ch * MDOC + b * TKv + tid];
        if (tid + 256 < TKv) e1s += g_ep[ch * MDOC + b * TKv + tid + 256];
    }
    float e1 = (tid + 256 < TKv) ? e1s : -1e30f;

    float m = fmaxf(e0, e1);
    red[tid] = m; __syncthreads();
    for (int s = 128; s > 0; s >>= 1) { if (tid < s) red[tid] = fmaxf(red[tid], red[tid + s]); __syncthreads(); }
    m = red[0]; __syncthreads();

    float p0 = expf(e0 - m) * mask[b * TKv + tid];
    float p1 = (tid + 256 < TKv) ? expf(e1 - m) * mask[b * TKv + tid + 256] : 0.f;
    red[tid] = p0 + p1; __syncthreads();
    for (int s = 128; s > 0; s >>= 1) { if (tid < s) red[tid] += red[tid + s]; __syncthreads(); }
    float inv = 1.f / red[0];

    float a0 = p0 * inv;
    g_a[b * TKv + tid] = a0;
    out_a[b * TKv + tid] = a0;
    out_cov[b * TKv + tid] = cov[b * TKv + tid] + a0;
    if (tid + 256 < TKv) {
        float a1 = p1 * inv;
        g_a[b * TKv + tid + 256] = a1;
        out_a[b * TKv + tid + 256] = a1;
        out_cov[b * TKv + tid + 256] = cov[b * TKv + tid + 256] + a1;
    }
}

// ---------------------------------------------------------------------------
// K3bc (fused): [0, B*NK) fmax rows (max(a*n2t) + rowsum); then (B,8) c_d
// t-split partials. Both depend only on a + inputs.
// ---------------------------------------------------------------------------
__global__ __launch_bounds__(256) void k_fmax_cd(
    const float* __restrict__ n2t, const float* __restrict__ enc)
{
    __shared__ float sA[256], sB[256];
    const int tid = threadIdx.x;
    int bid = blockIdx.x;

    if (bid < Bv * NKv) {
        // ---- fmax + rowsum ----
        const int b = bid / NKv;
        const float* nb = n2t + (size_t)bid * TKv;
        const float* ab = g_a + b * TKv;

        float x0 = nb[tid], a0 = ab[tid];
        float mx = a0 * x0, sm = x0;
        if (tid + 256 < TKv) {
            float x1 = nb[tid + 256], a1 = ab[tid + 256];
            mx = fmaxf(mx, a1 * x1);
            sm += x1;
        }
        mx = fmaxf(mx, 0.f);
        sA[tid] = mx; sB[tid] = sm; __syncthreads();
        for (int s = 128; s > 0; s >>= 1) {
            if (tid < s) {
                sA[tid] = fmaxf(sA[tid], sA[tid + s]);
                sB[tid] += sB[tid + s];
            }
            __syncthreads();
        }
        if (tid == 0) { g_fl[bid] = sA[0]; g_nrs[bid] = sB[0]; }
        return;
    }
    bid -= Bv * NKv;
    {
        // ---- c_d t-split partials ----
        const int b = bid >> 3, ks = bid & 7;
        if (tid < 50) sA[tid] = g_a[b * TKv + ks * 50 + tid];
        __syncthreads();

        const float* eb = enc + ((size_t)b * TKv + ks * 50) * 256 + tid;
        float acc = 0.f;
        #pragma unroll 10
        for (int t = 0; t < 50; t++) acc += sA[t] * eb[(size_t)t * 256];
        g_cdp[ks * 32768 + b * 256 + tid] = acc;
    }
}

// ---------------------------------------------------------------------------
// K5: flow normalize, node softmax chain, an2, cg/cg2, S4, p_gen.
// ---------------------------------------------------------------------------
__global__ __launch_bounds__(256) void k_node1(
    const float* __restrict__ encn,
    const float* __restrict__ maskn,
    const float* __restrict__ flow,
    const float* __restrict__ graph,
    const float* __restrict__ Wpg, const float* __restrict__ bpg,
    float* __restrict__ out_cd, float* __restrict__ out_cg,
    float* __restrict__ out_cg2, float* __restrict__ out_pgen,
    float* __restrict__ out_flow)
{
    const int b = blockIdx.x, tid = threadIdx.x;
    __shared__ float ans[NKv], an2s[NKv], red[256];

    // flow_next = g_fl / sum
    float fv = (tid < NKv) ? g_fl[b * NKv + tid] : 0.f;
    red[tid] = fv; __syncthreads();
    for (int s = 128; s > 0; s >>= 1) { if (tid < s) red[tid] += red[tid + s]; __syncthreads(); }
    float fs = red[0]; __syncthreads();
    if (tid < NKv) out_flow[b * NKv + tid] = fv / fs;

    // c_d = sum of 8 t-split partials
    float cd = 0.f;
    #pragma unroll
    for (int i = 0; i < 8; i++) cd += g_cdp[i * 32768 + b * 256 + tid];
    g_cd[b * 256 + tid] = cd;
    out_cd[b * 256 + tid] = cd;

    // node softmax -> flow-weighted renorm
    float v = -1e30f;
    if (tid < NKv) {
        v = 0.f;
        #pragma unroll
        for (int ch = 0; ch < 4; ch++) v += g_enp[ch * MNODE + b * NKv + tid];
    }
    red[tid] = v; __syncthreads();
    for (int s = 128; s > 0; s >>= 1) { if (tid < s) red[tid] = fmaxf(red[tid], red[tid + s]); __syncthreads(); }
    float m = red[0]; __syncthreads();

    float p = (tid < NKv) ? expf(v - m) * maskn[b * NKv + tid] : 0.f;
    red[tid] = p; __syncthreads();
    for (int s = 128; s > 0; s >>= 1) { if (tid < s) red[tid] += red[tid + s]; __syncthreads(); }
    float S = red[0]; __syncthreads();
    p = (tid < NKv) ? (p / S) * flow[b * NKv + tid] : 0.f;
    red[tid] = p; __syncthreads();
    for (int s = 128; s > 0; s >>= 1) { if (tid < s) red[tid] += red[tid + s]; __syncthreads(); }
    float S2 = red[0]; __syncthreads();
    if (tid < NKv) {
        ans[tid] = p / S2;
        g_ans[b * NKv + tid] = ans[tid];
    }
    __syncthreads();

    // S4 = sum_n an[n] * rowsum_n (for a_n2t normalization)
    float s4p = (tid < NKv) ? ans[tid] * g_nrs[b * NKv + tid] : 0.f;
    red[tid] = s4p; __syncthreads();
    for (int s = 128; s > 0; s >>= 1) { if (tid < s) red[tid] += red[tid + s]; __syncthreads(); }
    if (tid == 0) g_inv4[b] = 1.f / red[0];
    __syncthreads();

    // an2 = (ans @ graph) * mask, renormalized
    float q = 0.f;
    if (tid < NKv) {
        const float* gb = graph + (size_t)b * NKv * NKv + tid;
        #pragma unroll
        for (int n = 0; n < NKv; n++) q += ans[n] * gb[n * NKv];
        q *= maskn[b * NKv + tid];
    }
    red[tid] = q; __syncthreads();
    for (int s = 128; s > 0; s >>= 1) { if (tid < s) red[tid] += red[tid + s]; __syncthreads(); }
    float S3 = red[0]; __syncthreads();
    if (tid < NKv) an2s[tid] = q / S3;
    __syncthreads();

    // c_g and c_g2 in one pass over encn
    float cg = 0.f, cg2 = 0.f;
    {
        const float* enb = encn + (size_t)b * NKv * 256 + tid;
        #pragma unroll
        for (int n = 0; n < NKv; n++) {
            float e = enb[n * 256];
            cg  += ans[n]  * e;
            cg2 += an2s[n] * e;
        }
    }
    g_cg[b * 256 + tid] = cg;   out_cg[b * 256 + tid] = cg;
    g_cg2[b * 256 + tid] = cg2; out_cg2[b * 256 + tid] = cg2;

    // p_gen
    float hvv = g_h[b * 256 + tid], cvv = g_c[b * 256 + tid];
    float xvv = g_x[b * 256 + tid];
    float part = cd  * Wpg[tid]        + cg  * Wpg[256 + tid]
               + cg2 * Wpg[512 + tid]  + hvv * Wpg[768 + tid]
               + cvv * Wpg[1024 + tid] + xvv * Wpg[1280 + tid];
    red[tid] = part; __syncthreads();
    for (int s = 128; s > 0; s >>= 1) { if (tid < s) red[tid] += red[tid + s]; __syncthreads(); }
    if (tid == 0) {
        float pg = sigm(red[0] + bpg[0]);
        g_pg[b] = pg; out_pgen[b] = pg;
    }
}

// ---------------------------------------------------------------------------
// K5b+K6 (fused): [0, 2B) a_n2t scatter chunks; [2B, 6B) out1 col-chunks.
// Both depend only on k_node1's outputs.
// ---------------------------------------------------------------------------
__global__ __launch_bounds__(256) void k_ant_o1(
    const float* __restrict__ n2t,
    const float* __restrict__ W1, const float* __restrict__ b1,
    float* __restrict__ out_ant)
{
    __shared__ float cat[1024];
    __shared__ float red[256];
    const int tid = threadIdx.x;
    int bid = blockIdx.x;

    if (bid < 2 * Bv) {
        // ---- a_n2t ----
        const int b = bid >> 1, ks = bid & 1;
        if (tid < NKv) red[tid] = g_ans[b * NKv + tid];
        __syncthreads();
        if (tid < 200) {
            const int t = ks * 200 + tid;
            const float* nb = n2t + (size_t)b * NKv * TKv + t;
            float at = 0.f;
            #pragma unroll
            for (int n = 0; n < NKv; n++) at += red[n] * nb[n * TKv];
            out_ant[b * TKv + t] = at * g_inv4[b];
        }
        return;
    }
    bid -= 2 * Bv;
    {
        // ---- out1 ----
        const int b = bid >> 2, cc = bid & 3;
        cat[tid]       = g_h  [b * 256 + tid];
        cat[256 + tid] = g_cd [b * 256 + tid];
        cat[512 + tid] = g_cg [b * 256 + tid];
        cat[768 + tid] = g_cg2[b * 256 + tid];
        __syncthreads();

        const int lane = tid & 63, kq = tid >> 6;
        const int col = cc * 64 + lane;
        const float* w  = W1 + (size_t)(kq * 256) * 256 + col;
        const float* cs = cat + kq * 256;
        float acc = 0.f;
        #pragma unroll 8
        for (int k = 0; k < 256; k++) acc += cs[k] * w[(size_t)k * 256];
        red[tid] = acc; __syncthreads();

        if (tid < 64) {
            float o = b1[cc * 64 + tid]
                    + red[tid] + red[64 + tid] + red[128 + tid] + red[192 + tid];
            g_o1[b * 256 + cc * 64 + tid] = o;
            g_o1b[b * 256 + cc * 64 + tid] = f2bf(o);
        }
    }
}

// ---------------------------------------------------------------------------
// K7 (MFMA): logits chunk + fused per-row (max, sumexp) partial.
// ---------------------------------------------------------------------------
__global__ __launch_bounds__(256) void k_logits(const float* __restrict__ b2)
{
    const int v0 = blockIdx.x * 64;
    const int tid = threadIdx.x;
    const int lane = tid & 63, wave = tid >> 6;
    const int nlow = lane & 15, quad = lane >> 4;

    const u16* a0p = g_o1b + (wave * 32 + nlow) * 256 + quad * 8;
    const u16* a1p = a0p + 16 * 256;
    const u16* bbase = g_W2t + (size_t)(v0 + nlow) * 256 + quad * 8;

    const f32x4 zf = {0.f, 0.f, 0.f, 0.f};
    f32x4 acc0[4], acc1[4];
    #pragma unroll
    for (int i = 0; i < 4; i++) { acc0[i] = zf; acc1[i] = zf; }

    for (int k0 = 0; k0 < 256; k0 += 32) {
        bf16x8 a0 = *(const bf16x8*)(a0p + k0);
        bf16x8 a1 = *(const bf16x8*)(a1p + k0);
        #pragma unroll
        for (int nt = 0; nt < 4; nt++) {
            bf16x8 bf = *(const bf16x8*)(bbase + (size_t)nt * 4096 + k0);
            acc0[nt] = __builtin_amdgcn_mfma_f32_16x16x32_bf16(a0, bf, acc0[nt], 0, 0, 0);
            acc1[nt] = __builtin_amdgcn_mfma_f32_16x16x32_bf16(a1, bf, acc1[nt], 0, 0, 0);
        }
    }

    float bbv[4]; bool val[4];
    #pragma unroll
    for (int nt = 0; nt < 4; nt++) {
        int v = v0 + nt * 16 + nlow;
        val[nt] = v < Vv;
        bbv[nt] = val[nt] ? b2[v] : 0.f;
    }

    #pragma unroll
    for (int mi = 0; mi < 2; mi++) {
        #pragma unroll
        for (int r = 0; r < 4; r++) {
            const int row = wave * 32 + mi * 16 + quad * 4 + r;
            float x[4];
            #pragma unroll
            for (int nt = 0; nt < 4; nt++) {
                float xv = (mi ? acc1[nt][r] : acc0[nt][r]) + bbv[nt];
                if (val[nt]) g_logits[(size_t)row * Vv + v0 + nt * 16 + nlow] = xv;
                x[nt] = val[nt] ? xv : -1e30f;
            }
            float m = fmaxf(fmaxf(x[0], x[1]), fmaxf(x[2], x[3]));
            m = fmaxf(m, __shfl_xor(m, 1, 64));
            m = fmaxf(m, __shfl_xor(m, 2, 64));
            m = fmaxf(m, __shfl_xor(m, 4, 64));
            m = fmaxf(m, __shfl_xor(m, 8, 64));
            float s = expf(x[0] - m) + expf(x[1] - m)
                    + expf(x[2] - m) + expf(x[3] - m);
            s += __shfl_xor(s, 1, 64);
            s += __shfl_xor(s, 2, 64);
            s += __shfl_xor(s, 4, 64);
            s += __shfl_xor(s, 8, 64);
            if (nlow == 0) {
                g_vpp[((size_t)row * NBLK + blockIdx.x) * 2]     = m;
                g_vpp[((size_t)row * NBLK + blockIdx.x) * 2 + 1] = s;
            }
        }
    }
}

// ---------------------------------------------------------------------------
// K8 (fused): merge NBLK (max,sum) pairs (redundant per block, L2-hot),
// write exp(x-M)*pg/S for the chunk, then scatter the pointer-adds whose
// vocd targets land in THIS chunk (intra-block ordering: fence + barrier).
// ---------------------------------------------------------------------------
__global__ __launch_bounds__(256) void k_vwrite_sc(
    float* __restrict__ outF, const int* __restrict__ vocd)
{
    const int b = blockIdx.x, ks = blockIdx.y, tid = threadIdx.x;
    __shared__ float rm[256], rs[256];

    float M = -1e30f, S = 0.f;
    for (int i = tid; i < NBLK; i += 256)
        ms_merge(M, S, g_vpp[((size_t)b * NBLK + i) * 2],
                       g_vpp[((size_t)b * NBLK + i) * 2 + 1]);
    rm[tid] = M; rs[tid] = S; __syncthreads();
    for (int off = 128; off > 0; off >>= 1) {
        if (tid < off) {
            float m1 = rm[tid], s1 = rs[tid];
            ms_merge(m1, s1, rm[tid + off], rs[tid + off]);
            rm[tid] = m1; rs[tid] = s1;
        }
        __syncthreads();
    }
    M = rm[0];
    const float inv = g_pg[b] / rs[0];

    const int base = ks * CHUNKv;
    const int end  = min(base + CHUNKv, Vv);
    const int n4   = (end - base) >> 2;
    const float4* L4 = (const float4*)(g_logits + (size_t)b * Vv + base);
    float4* O4 = (float4*)(outF + (size_t)b * Vv + base);

    for (int i = tid; i < n4; i += 256) {
        float4 x = L4[i];
        float4 r;
        r.x = expf(x.x - M) * inv;
        r.y = expf(x.y - M) * inv;
        r.z = expf(x.z - M) * inv;
        r.w = expf(x.w - M) * inv;
        O4[i] = r;
    }

    __threadfence();
    __syncthreads();

    // pointer scatter for targets inside this chunk only
    const float omp = 1.f - g_pg[b];
    for (int t = tid; t < TKv; t += 256) {
        int v = vocd[b * TKv + t];
        if (v >= base && v < base + CHUNKv)
            atomicAdd(outF + (size_t)b * Vv + v, omp * g_a[b * TKv + t]);
    }
}

// ---------------------------------------------------------------------------

extern "C" void kernel_launch(void* const* d_in, const int* in_sizes, int n_in,
                              void* d_out, int out_size, void* d_ws, size_t ws_size,
                              hipStream_t stream)
{
    (void)in_sizes; (void)n_in; (void)out_size; (void)d_ws; (void)ws_size;

    const int*   y      = (const int*)d_in[0];
    const float* h_prev = (const float*)d_in[1];
    const float* c_prev = (const float*)d_in[2];
    const float* enc    = (const float*)d_in[3];
    const float* encn   = (const float*)d_in[4];
    const float* mask   = (const float*)d_in[5];
    const float* maskn  = (const float*)d_in[6];
    const float* ctd    = (const float*)d_in[7];
    const float* ctg    = (const float*)d_in[8];
    const float* ctg2   = (const float*)d_in[9];
    const float* cov    = (const float*)d_in[10];
    const float* flow   = (const float*)d_in[11];
    const float* n2t    = (const float*)d_in[12];
    const float* graph  = (const float*)d_in[13];
    const int*   vocd   = (const int*)d_in[14];
    // d_in[15] = step (unused)
    const float* emb    = (const float*)d_in[16];
    const float* Wx     = (const float*)d_in[17];
    const float* bx     = (const float*)d_in[18];
    const float* Wi     = (const float*)d_in[19];
    const float* Wh     = (const float*)d_in[20];
    const float* bi     = (const float*)d_in[21];
    const float* bh     = (const float*)d_in[22];
    const float* Whd    = (const float*)d_in[23];
    const float* Wsd    = (const float*)d_in[24];
    const float* wcdw   = (const float*)d_in[25];
    const float* vd     = (const float*)d_in[26];
    const float* bd     = (const float*)d_in[27];
    const float* Wn     = (const float*)d_in[28];
    const float* Wsf    = (const float*)d_in[29];
    const float* vf     = (const float*)d_in[30];
    const float* bfv    = (const float*)d_in[31];
    const float* Wpg    = (const float*)d_in[32];
    const float* bpg    = (const float*)d_in[33];
    const float* W1     = (const float*)d_in[34];
    const float* b1     = (const float*)d_in[35];
    const float* W2     = (const float*)d_in[36];
    const float* b2     = (const float*)d_in[37];

    float* o = (float*)d_out;                 // FLOAT32 output
    float* o_final = o;                       // 6,400,000
    float* o_h     = o + 6400000;
    float* o_c     = o + 6432768;
    float* o_cd    = o + 6465536;
    float* o_cg    = o + 6498304;
    float* o_cg2   = o + 6531072;
    float* o_a     = o + 6563840;
    float* o_ant   = o + 6615040;
    float* o_pg    = o + 6666240;
    float* o_cov   = o + 6666368;
    float* o_fl    = o + 6717568;

    // 1. all input-only preprocessing (weight tc, enc cvt, x-partials)
    k_prep<<<dim3(NB_PREP), dim3(256), 0, stream>>>(
        Whd, Wn, W2, enc, encn, y, ctd, ctg, ctg2, emb, Wx);

    // 2-3. LSTM front-end chain
    k_gates<<<dim3(Bv, 4), dim3(256), 0, stream>>>(h_prev, Wi, Wh, bi, bh, bx);

    k_cellsd<<<dim3(Bv, 2), dim3(256), 0, stream>>>(c_prev, Wsd, Wsf, o_h, o_c);

    // 4. doc + node attention scores in one launch
    k_scores_all<<<dim3(MDOC / 128 + MNODE / 128, 4), dim3(256), 0, stream>>>(
        bd, bfv, cov, wcdw, vd, vf);

    // 5. doc softmax
    k_doc<<<dim3(Bv), dim3(256), 0, stream>>>(mask, cov, o_a, o_cov);

    // 6. flow-max/rowsum + c_d partials
    k_fmax_cd<<<dim3(Bv * NKv + Bv * 8), dim3(256), 0, stream>>>(n2t, enc);

    // 7. node chain + p_gen + flow normalize
    k_node1<<<dim3(Bv), dim3(256), 0, stream>>>(
        encn, maskn, flow, graph, Wpg, bpg,
        o_cd, o_cg, o_cg2, o_pg, o_fl);

    // 8. a_n2t + out1
    k_ant_o1<<<dim3(2 * Bv + 4 * Bv), dim3(256), 0, stream>>>(n2t, W1, b1, o_ant);

    // 9. logits + per-row (max,sum) partials
    k_logits<<<dim3(NBLK), dim3(256), 0, stream>>>(b2);

    // 10. softmax write + pointer scatter
    k_vwrite_sc<<<dim3(Bv, NSv), dim3(256), 0, stream>>>(o_final, vocd);
}

// Round 10
// 442.563 us; speedup vs baseline: 1.4577x; 1.4577x over previous
//
#include <hip/hip_runtime.h>
#include <stdint.h>

// ---------------------------------------------------------------------------
// LSTM pointer-generator decoder step, B=128 TK=400 NK=50 H=E=256 V=50000.
// Round 16: R15's k_vwrite_sc REGRESSED 210us (222us dispatch, hbm 183GB/s):
// device-scope __threadfence in 2048 blocks + atomics on freshly-written
// lines serialized the 25.6MB output stream. Fix: split back into k_vwrite
// (merge + float4 write, no fence/atomics — R14-proven) + separate
// k_scatter launch (stream order provides the write->scatter ordering).
// All other R15 launch fusions kept (they saved ~25-30us vs R13).
// ---------------------------------------------------------------------------

typedef unsigned short u16;
typedef unsigned int   u32;

#define Bv  128
#define TKv 400
#define NKv 50
#define Hv  256
#define Vv  50000
#define VPAD 50176   // 50000 padded to multiple of 128
#define NSv 16
#define CHUNKv 3136  // VPAD / NSv
#define MDOC (Bv * TKv)   // 51200
#define MNODE (Bv * NKv)  // 6400
#define NBLK (VPAD / 64)  // 784 logits col-blocks

// k_prep block ranges
#define NB_TCW2 ((VPAD / 32) * 8)          // 12544
#define NB_PAIR 128                        // 2 x (8x8)
#define NB_CVT  2148                       // 2048 enc + 100 encn
#define NB_KX   (Bv * 4)                   // 512
#define NB_PREP (NB_TCW2 + NB_PAIR + NB_CVT + NB_KX)

typedef __attribute__((ext_vector_type(8))) short bf16x8;
typedef __attribute__((ext_vector_type(4))) float f32x4;

// ---- module-global workspace (no d_ws dependency) -------------------------
__device__ float g_x[32768];      // x = cat @ Wx + bx
__device__ float g_xp[4 * 32768]; // x K-partials
__device__ float g_gates[131072]; // LSTM gates [B,4H]
__device__ float g_h[32768];      // h_new
__device__ float g_c[32768];      // c_new
__device__ float g_sdp[2 * 32768];// s_hat@Wsd partials (no bias)
__device__ float g_sfp[2 * 32768];// s_hat@Wsf partials (no bias)
__device__ float g_ep[4 * MDOC];  // doc score partials (4 col-chunks)
__device__ float g_enp[4 * MNODE];// node score partials
__device__ float g_a[51200];      // doc attention a
__device__ float g_cd[32768];     // c_d
__device__ float g_cdp[8 * 32768];// c_d t-split partials (8 chunks of 50)
__device__ float g_cg[32768];     // c_g
__device__ float g_cg2[32768];    // c_g2
__device__ float g_pg[128];       // p_gen
__device__ float g_ans[MNODE];    // node attention an
__device__ float g_inv4[128];     // 1/S4 for a_n2t
__device__ float g_fl[MNODE];     // unnormalized flow
__device__ float g_nrs[MNODE];    // n2t row sums
__device__ float g_o1[32768];     // out1 (f32)
__device__ __attribute__((aligned(16))) u16 g_o1b[32768]; // out1 bf16
__device__ float g_vpp[(size_t)2 * Bv * NBLK]; // per-(row,blk) (max,sum)
__device__ float g_logits[6400000];        // f32 logits (25.6 MB)
__device__ u16   g_Wdt[256 * 256];         // Whd^T bf16 [n][k]
__device__ u16   g_Wnt[256 * 256];         // Wn^T  bf16 [n][k]
__device__ u16   g_W2t[(size_t)VPAD * 256];// W2^T  bf16 [v][k] (25.7 MB)
__device__ u16   g_encb[(size_t)Bv * TKv * 256]; // enc bf16 (26.2 MB)
__device__ u16   g_encnb[(size_t)Bv * NKv * 256];// encn bf16 (3.3 MB)

__device__ __forceinline__ float sigm(float x) { return 1.f / (1.f + expf(-x)); }

__device__ __forceinline__ u16 f2bf(float f) {
    u32 u = __float_as_uint(f);
    return (u16)((u + 0x7fffu + ((u >> 16) & 1u)) >> 16);  // RNE
}

__device__ __forceinline__ bf16x8 cvt8(const float* __restrict__ p) {
    const float4 a = *(const float4*)p;
    const float4 b = *(const float4*)(p + 4);
    bf16x8 r;
    r[0] = (short)f2bf(a.x); r[1] = (short)f2bf(a.y);
    r[2] = (short)f2bf(a.z); r[3] = (short)f2bf(a.w);
    r[4] = (short)f2bf(b.x); r[5] = (short)f2bf(b.y);
    r[6] = (short)f2bf(b.z); r[7] = (short)f2bf(b.w);
    return r;
}

// tanh via exp; clamp so exp never overflows (tanh saturated anyway)
__device__ __forceinline__ float fast_tanh(float x) {
    x = fminf(fmaxf(x, -15.f), 15.f);
    float e = __expf(2.f * x);
    return (e - 1.f) / (e + 1.f);
}

// online (max,sum) merge: (m1,s1) <- (m1,s1) U (m2,s2)
__device__ __forceinline__ void ms_merge(float& m1, float& s1, float m2, float s2) {
    float M = fmaxf(m1, m2);
    s1 = s1 * expf(m1 - M) + s2 * expf(m2 - M);
    m1 = M;
}

// ---------------------------------------------------------------------------
// K0 (fused prep): all input-only preprocessing in ONE launch.
//   [0, NB_TCW2)              : W2 [256][50000] -> W2^T bf16 [VPAD][256]
//   [NB_TCW2, +NB_PAIR)       : Whd / Wn 256x256 transpose-casts
//   [.., +NB_CVT)             : enc / encn streaming f32->bf16
//   [.., +NB_KX)              : x K-partials (B,4)
// ---------------------------------------------------------------------------
__global__ __launch_bounds__(256) void k_prep(
    const float* __restrict__ Whd, const float* __restrict__ Wn,
    const float* __restrict__ W2,
    const float* __restrict__ enc, const float* __restrict__ encn,
    const int* __restrict__ y,
    const float* __restrict__ ctd, const float* __restrict__ ctg,
    const float* __restrict__ ctg2, const float* __restrict__ emb,
    const float* __restrict__ Wx)
{
    __shared__ float tile[32][33];
    const int tid = threadIdx.x;
    int bid = blockIdx.x;

    if (bid < NB_TCW2) {
        // ---- W2 transpose-cast ----
        const int n0 = (bid % (VPAD / 32)) * 32, k0 = (bid / (VPAD / 32)) * 32;
        const int tx = tid & 31, ty = tid >> 5;
        #pragma unroll
        for (int i = 0; i < 32; i += 8) {
            int k = k0 + ty + i, n = n0 + tx;
            tile[ty + i][tx] = (n < Vv) ? W2[(size_t)k * Vv + n] : 0.f;
        }
        __syncthreads();
        #pragma unroll
        for (int i = 0; i < 32; i += 8) {
            int n = n0 + ty + i, k = k0 + tx;
            g_W2t[(size_t)n * 256 + k] = f2bf(tile[tx][ty + i]);
        }
        return;
    }
    bid -= NB_TCW2;
    if (bid < NB_PAIR) {
        // ---- Whd / Wn transpose-cast ----
        const int z = bid >> 6, rem = bid & 63;
        const float* src = z ? Wn : Whd;
        u16* dst = z ? g_Wnt : g_Wdt;
        const int n0 = (rem & 7) * 32, k0 = (rem >> 3) * 32;
        const int tx = tid & 31, ty = tid >> 5;
        #pragma unroll
        for (int i = 0; i < 32; i += 8)
            tile[ty + i][tx] = src[(size_t)(k0 + ty + i) * 256 + n0 + tx];
        __syncthreads();
        #pragma unroll
        for (int i = 0; i < 32; i += 8)
            dst[(size_t)(n0 + ty + i) * 256 + k0 + tx] = f2bf(tile[tx][ty + i]);
        return;
    }
    bid -= NB_PAIR;
    if (bid < NB_CVT) {
        // ---- enc / encn f32 -> bf16 ----
        if (bid < 2048) {
            const int n8 = Bv * TKv * 256 / 8;
            int i = bid * 256 + tid;
            for (; i < n8; i += 2048 * 256)
                *(bf16x8*)(g_encb + (size_t)i * 8) = cvt8(enc + (size_t)i * 8);
        } else {
            const int n8 = Bv * NKv * 256 / 8;
            int i = (bid - 2048) * 256 + tid;
            for (; i < n8; i += 100 * 256)
                *(bf16x8*)(g_encnb + (size_t)i * 8) = cvt8(encn + (size_t)i * 8);
        }
        return;
    }
    bid -= NB_CVT;
    {
        // ---- x K-partials ----
        const int b = bid >> 2, ks = bid & 3, j = tid;
        float* cs = &tile[0][0];
        float v;
        if      (ks == 0) v = ctd [b * 256 + j];
        else if (ks == 1) v = ctg [b * 256 + j];
        else if (ks == 2) v = ctg2[b * 256 + j];
        else              v = emb[(size_t)y[b] * 256 + j];
        cs[j] = v;
        __syncthreads();

        float acc = 0.f;
        const float* w = Wx + (size_t)(ks * 256) * 256 + j;
        #pragma unroll 8
        for (int k = 0; k < 256; k++) acc += cs[k] * w[(size_t)k * 256];
        g_xp[ks * 32768 + b * 256 + j] = acc;
    }
}

// ---------------------------------------------------------------------------
// K1b: gates = x@Wi + h@Wh + bi + bh. grid (B, 4 col-chunks).
// ---------------------------------------------------------------------------
__global__ __launch_bounds__(256) void k_gates(
    const float* __restrict__ h_prev,
    const float* __restrict__ Wi, const float* __restrict__ Wh,
    const float* __restrict__ bi, const float* __restrict__ bh,
    const float* __restrict__ bx)
{
    const int b = blockIdx.x, cc = blockIdx.y, j = threadIdx.x;
    __shared__ float xs[256], hs[256];

    float xv = bx[j] + g_xp[b * 256 + j] + g_xp[32768 + b * 256 + j]
             + g_xp[65536 + b * 256 + j] + g_xp[98304 + b * 256 + j];
    xs[j] = xv;
    if (cc == 0) g_x[b * 256 + j] = xv;
    hs[j] = h_prev[b * 256 + j];
    __syncthreads();

    const int col = cc * 256 + j;
    float acc = bi[col] + bh[col];
    const float* wi = Wi + col;
    const float* wh = Wh + col;
    #pragma unroll 8
    for (int k = 0; k < 256; k++)
        acc += xs[k] * wi[(size_t)k * 1024] + hs[k] * wh[(size_t)k * 1024];
    g_gates[b * 1024 + col] = acc;
}

// ---------------------------------------------------------------------------
// K1c: LSTM elementwise + sd/sf K-partials. grid (B, 2).
// ---------------------------------------------------------------------------
__global__ __launch_bounds__(256) void k_cellsd(
    const float* __restrict__ c_prev,
    const float* __restrict__ Wsd, const float* __restrict__ Wsf,
    float* __restrict__ out_h, float* __restrict__ out_c)
{
    const int b = blockIdx.x, ks = blockIdx.y, j = threadIdx.x;
    __shared__ float sh[256];

    const float* gb = g_gates + b * 1024;
    float gi_ = gb[j], gf_ = gb[256 + j], gg_ = gb[512 + j], go_ = gb[768 + j];
    float cp = c_prev[b * 256 + j];
    float cn = sigm(gf_) * cp + sigm(gi_) * tanhf(gg_);
    float hn = sigm(go_) * tanhf(cn);
    if (ks == 0) {
        g_h[b * 256 + j] = hn;  g_c[b * 256 + j] = cn;
        out_h[b * 256 + j] = hn; out_c[b * 256 + j] = cn;
    }
    sh[j] = (ks == 0) ? hn : cn;   // s_hat rows [0,256) = h, [256,512) = c
    __syncthreads();

    float asd = 0.f, asf = 0.f;
    const float* wd = Wsd + (size_t)(ks * 256) * 256 + j;
    const float* wf = Wsf + (size_t)(ks * 256) * 256 + j;
    #pragma unroll 8
    for (int k = 0; k < 256; k++) {
        float sv = sh[k];
        asd += sv * wd[(size_t)k * 256];
        asf += sv * wf[(size_t)k * 256];
    }
    g_sdp[ks * 32768 + b * 256 + j] = asd;
    g_sfp[ks * 32768 + b * 256 + j] = asf;
}

// ---------------------------------------------------------------------------
// K2 (MFMA): doc + node score e-PARTIALS in ONE launch. grid (450, 4):
// blockIdx.x < 400 -> doc rows, else node rows. LDS-staged 64-col W chunk
// ([64][264] pad -> 2-way conflicts only), wave = 2 M-tiles x 4 N-tiles,
// A double-buffered from global.
// ---------------------------------------------------------------------------
__global__ __launch_bounds__(256) void k_scores_all(
    const float* __restrict__ bd,  const float* __restrict__ bfv,
    const float* __restrict__ cov, const float* __restrict__ wcdw,
    const float* __restrict__ vd,  const float* __restrict__ vf)
{
    const int tid = threadIdx.x;
    const int lane = tid & 63, w = tid >> 6;
    const int nlow = lane & 15, quad = lane >> 4;
    const int c0 = blockIdx.y * 64;

    const bool isdoc = blockIdx.x < (MDOC / 128);
    const int bx = isdoc ? blockIdx.x : blockIdx.x - MDOC / 128;
    const int R = isdoc ? TKv : NKv;
    const int Mtot = isdoc ? MDOC : MNODE;
    const u16* srcb = isdoc ? g_encb : g_encnb;
    const u16* Wt   = isdoc ? g_Wdt : g_Wnt;
    const float* addv0 = isdoc ? g_sdp : g_sfp;
    const float* addv1 = isdoc ? g_sdp + 32768 : g_sfp + 32768;
    const float* abias = isdoc ? bd : bfv;
    const float* covp  = isdoc ? cov : nullptr;
    const float* wcw   = isdoc ? wcdw : nullptr;
    const float* vv    = isdoc ? vd : vf;
    float* eout        = isdoc ? g_ep : g_enp;

    __shared__ u16 Bs[64][264];
    {
        const u16* wsrc = Wt + (size_t)c0 * 256;
        #pragma unroll
        for (int j = 0; j < 8; j++) {
            int chunk = tid + j * 256;
            int row = chunk >> 5, c16 = chunk & 31;
            *(bf16x8*)(&Bs[row][c16 * 8]) =
                *(const bf16x8*)(wsrc + row * 256 + c16 * 8);
        }
    }
    __syncthreads();

    const int rowbase = bx * 128 + w * 32;
    const u16* a0 = srcb + (size_t)(rowbase + nlow) * 256 + quad * 8;
    const u16* a1 = a0 + 16 * 256;

    const f32x4 zf = {0.f, 0.f, 0.f, 0.f};
    f32x4 acc[2][4];
    #pragma unroll
    for (int mi = 0; mi < 2; mi++)
        #pragma unroll
        for (int ni = 0; ni < 4; ni++) acc[mi][ni] = zf;

    bf16x8 af0 = *(const bf16x8*)(a0);
    bf16x8 af1 = *(const bf16x8*)(a1);
    for (int k0 = 0; k0 < 256; k0 += 32) {
        const int kn = (k0 + 32) & 255;   // wrap: last iter re-reads k=0 (discarded)
        bf16x8 nf0 = *(const bf16x8*)(a0 + kn);
        bf16x8 nf1 = *(const bf16x8*)(a1 + kn);
        bf16x8 bf[4];
        #pragma unroll
        for (int ni = 0; ni < 4; ni++)
            bf[ni] = *(const bf16x8*)(&Bs[ni * 16 + nlow][k0 + quad * 8]);
        #pragma unroll
        for (int ni = 0; ni < 4; ni++) {
            acc[0][ni] = __builtin_amdgcn_mfma_f32_16x16x32_bf16(af0, bf[ni], acc[0][ni], 0, 0, 0);
            acc[1][ni] = __builtin_amdgcn_mfma_f32_16x16x32_bf16(af1, bf[ni], acc[1][ni], 0, 0, 0);
        }
        af0 = nf0; af1 = nf1;
    }

    // epilogue: row = rowbase + mi*16 + quad*4 + r, col = c0 + ni*16 + nlow
    #pragma unroll
    for (int mi = 0; mi < 2; mi++) {
        float covt[4]; int bidx[4];
        #pragma unroll
        for (int r = 0; r < 4; r++) {
            int row = rowbase + mi * 16 + quad * 4 + r;
            covt[r] = covp ? covp[row] : 0.f;
            bidx[r] = row / R;
        }
        float s4[4] = {0.f, 0.f, 0.f, 0.f};
        #pragma unroll
        for (int ni = 0; ni < 4; ni++) {
            int col = c0 + ni * 16 + nlow;
            float vvc = vv[col];
            float ab  = abias[col];
            float wcc = wcw ? wcw[col] : 0.f;
            #pragma unroll
            for (int r = 0; r < 4; r++) {
                float adc = addv0[bidx[r] * 256 + col] + addv1[bidx[r] * 256 + col] + ab;
                s4[r] += vvc * fast_tanh(acc[mi][ni][r] + adc + covt[r] * wcc);
            }
        }
        #pragma unroll
        for (int r = 0; r < 4; r++) {
            float s = s4[r];
            s += __shfl_xor(s, 1, 64);
            s += __shfl_xor(s, 2, 64);
            s += __shfl_xor(s, 4, 64);
            s += __shfl_xor(s, 8, 64);
            int row = rowbase + mi * 16 + quad * 4 + r;
            if (nlow == 0)
                eout[(size_t)blockIdx.y * Mtot + row] = s;
        }
    }
}

// ---------------------------------------------------------------------------
// K3: doc softmax (+mask renorm): sums the 4 e-partials, a, coverage_next.
// ---------------------------------------------------------------------------
__global__ __launch_bounds__(256) void k_doc(
    const float* __restrict__ mask,
    const float* __restrict__ cov,
    float* __restrict__ out_a, float* __restrict__ out_cov)
{
    const int b = blockIdx.x, tid = threadIdx.x;
    __shared__ float red[256];

    float e0 = 0.f, e1s = 0.f;
    #pragma unroll
    for (int ch = 0; ch < 4; ch++) {
        e0 += g_ep[ch * MDOC + b * TKv + tid];
        if (tid + 256 < TKv) e1s += g_ep[ch * MDOC + b * TKv + tid + 256];
    }
    float e1 = (tid + 256 < TKv) ? e1s : -1e30f;

    float m = fmaxf(e0, e1);
    red[tid] = m; __syncthreads();
    for (int s = 128; s > 0; s >>= 1) { if (tid < s) red[tid] = fmaxf(red[tid], red[tid + s]); __syncthreads(); }
    m = red[0]; __syncthreads();

    float p0 = expf(e0 - m) * mask[b * TKv + tid];
    float p1 = (tid + 256 < TKv) ? expf(e1 - m) * mask[b * TKv + tid + 256] : 0.f;
    red[tid] = p0 + p1; __syncthreads();
    for (int s = 128; s > 0; s >>= 1) { if (tid < s) red[tid] += red[tid + s]; __syncthreads(); }
    float inv = 1.f / red[0];

    float a0 = p0 * inv;
    g_a[b * TKv + tid] = a0;
    out_a[b * TKv + tid] = a0;
    out_cov[b * TKv + tid] = cov[b * TKv + tid] + a0;
    if (tid + 256 < TKv) {
        float a1 = p1 * inv;
        g_a[b * TKv + tid + 256] = a1;
        out_a[b * TKv + tid + 256] = a1;
        out_cov[b * TKv + tid + 256] = cov[b * TKv + tid + 256] + a1;
    }
}

// ---------------------------------------------------------------------------
// K3bc (fused): [0, B*NK) fmax rows (max(a*n2t) + rowsum); then (B,8) c_d
// t-split partials. Both depend only on a + inputs.
// ---------------------------------------------------------------------------
__global__ __launch_bounds__(256) void k_fmax_cd(
    const float* __restrict__ n2t, const float* __restrict__ enc)
{
    __shared__ float sA[256], sB[256];
    const int tid = threadIdx.x;
    int bid = blockIdx.x;

    if (bid < Bv * NKv) {
        // ---- fmax + rowsum ----
        const int b = bid / NKv;
        const float* nb = n2t + (size_t)bid * TKv;
        const float* ab = g_a + b * TKv;

        float x0 = nb[tid], a0 = ab[tid];
        float mx = a0 * x0, sm = x0;
        if (tid + 256 < TKv) {
            float x1 = nb[tid + 256], a1 = ab[tid + 256];
            mx = fmaxf(mx, a1 * x1);
            sm += x1;
        }
        mx = fmaxf(mx, 0.f);
        sA[tid] = mx; sB[tid] = sm; __syncthreads();
        for (int s = 128; s > 0; s >>= 1) {
            if (tid < s) {
                sA[tid] = fmaxf(sA[tid], sA[tid + s]);
                sB[tid] += sB[tid + s];
            }
            __syncthreads();
        }
        if (tid == 0) { g_fl[bid] = sA[0]; g_nrs[bid] = sB[0]; }
        return;
    }
    bid -= Bv * NKv;
    {
        // ---- c_d t-split partials ----
        const int b = bid >> 3, ks = bid & 7;
        if (tid < 50) sA[tid] = g_a[b * TKv + ks * 50 + tid];
        __syncthreads();

        const float* eb = enc + ((size_t)b * TKv + ks * 50) * 256 + tid;
        float acc = 0.f;
        #pragma unroll 10
        for (int t = 0; t < 50; t++) acc += sA[t] * eb[(size_t)t * 256];
        g_cdp[ks * 32768 + b * 256 + tid] = acc;
    }
}

// ---------------------------------------------------------------------------
// K5: flow normalize, node softmax chain, an2, cg/cg2, S4, p_gen.
// ---------------------------------------------------------------------------
__global__ __launch_bounds__(256) void k_node1(
    const float* __restrict__ encn,
    const float* __restrict__ maskn,
    const float* __restrict__ flow,
    const float* __restrict__ graph,
    const float* __restrict__ Wpg, const float* __restrict__ bpg,
    float* __restrict__ out_cd, float* __restrict__ out_cg,
    float* __restrict__ out_cg2, float* __restrict__ out_pgen,
    float* __restrict__ out_flow)
{
    const int b = blockIdx.x, tid = threadIdx.x;
    __shared__ float ans[NKv], an2s[NKv], red[256];

    // flow_next = g_fl / sum
    float fv = (tid < NKv) ? g_fl[b * NKv + tid] : 0.f;
    red[tid] = fv; __syncthreads();
    for (int s = 128; s > 0; s >>= 1) { if (tid < s) red[tid] += red[tid + s]; __syncthreads(); }
    float fs = red[0]; __syncthreads();
    if (tid < NKv) out_flow[b * NKv + tid] = fv / fs;

    // c_d = sum of 8 t-split partials
    float cd = 0.f;
    #pragma unroll
    for (int i = 0; i < 8; i++) cd += g_cdp[i * 32768 + b * 256 + tid];
    g_cd[b * 256 + tid] = cd;
    out_cd[b * 256 + tid] = cd;

    // node softmax -> flow-weighted renorm
    float v = -1e30f;
    if (tid < NKv) {
        v = 0.f;
        #pragma unroll
        for (int ch = 0; ch < 4; ch++) v += g_enp[ch * MNODE + b * NKv + tid];
    }
    red[tid] = v; __syncthreads();
    for (int s = 128; s > 0; s >>= 1) { if (tid < s) red[tid] = fmaxf(red[tid], red[tid + s]); __syncthreads(); }
    float m = red[0]; __syncthreads();

    float p = (tid < NKv) ? expf(v - m) * maskn[b * NKv + tid] : 0.f;
    red[tid] = p; __syncthreads();
    for (int s = 128; s > 0; s >>= 1) { if (tid < s) red[tid] += red[tid + s]; __syncthreads(); }
    float S = red[0]; __syncthreads();
    p = (tid < NKv) ? (p / S) * flow[b * NKv + tid] : 0.f;
    red[tid] = p; __syncthreads();
    for (int s = 128; s > 0; s >>= 1) { if (tid < s) red[tid] += red[tid + s]; __syncthreads(); }
    float S2 = red[0]; __syncthreads();
    if (tid < NKv) {
        ans[tid] = p / S2;
        g_ans[b * NKv + tid] = ans[tid];
    }
    __syncthreads();

    // S4 = sum_n an[n] * rowsum_n (for a_n2t normalization)
    float s4p = (tid < NKv) ? ans[tid] * g_nrs[b * NKv + tid] : 0.f;
    red[tid] = s4p; __syncthreads();
    for (int s = 128; s > 0; s >>= 1) { if (tid < s) red[tid] += red[tid + s]; __syncthreads(); }
    if (tid == 0) g_inv4[b] = 1.f / red[0];
    __syncthreads();

    // an2 = (ans @ graph) * mask, renormalized
    float q = 0.f;
    if (tid < NKv) {
        const float* gb = graph + (size_t)b * NKv * NKv + tid;
        #pragma unroll
        for (int n = 0; n < NKv; n++) q += ans[n] * gb[n * NKv];
        q *= maskn[b * NKv + tid];
    }
    red[tid] = q; __syncthreads();
    for (int s = 128; s > 0; s >>= 1) { if (tid < s) red[tid] += red[tid + s]; __syncthreads(); }
    float S3 = red[0]; __syncthreads();
    if (tid < NKv) an2s[tid] = q / S3;
    __syncthreads();

    // c_g and c_g2 in one pass over encn
    float cg = 0.f, cg2 = 0.f;
    {
        const float* enb = encn + (size_t)b * NKv * 256 + tid;
        #pragma unroll
        for (int n = 0; n < NKv; n++) {
            float e = enb[n * 256];
            cg  += ans[n]  * e;
            cg2 += an2s[n] * e;
        }
    }
    g_cg[b * 256 + tid] = cg;   out_cg[b * 256 + tid] = cg;
    g_cg2[b * 256 + tid] = cg2; out_cg2[b * 256 + tid] = cg2;

    // p_gen
    float hvv = g_h[b * 256 + tid], cvv = g_c[b * 256 + tid];
    float xvv = g_x[b * 256 + tid];
    float part = cd  * Wpg[tid]        + cg  * Wpg[256 + tid]
               + cg2 * Wpg[512 + tid]  + hvv * Wpg[768 + tid]
               + cvv * Wpg[1024 + tid] + xvv * Wpg[1280 + tid];
    red[tid] = part; __syncthreads();
    for (int s = 128; s > 0; s >>= 1) { if (tid < s) red[tid] += red[tid + s]; __syncthreads(); }
    if (tid == 0) {
        float pg = sigm(red[0] + bpg[0]);
        g_pg[b] = pg; out_pgen[b] = pg;
    }
}

// ---------------------------------------------------------------------------
// K5b+K6 (fused): [0, 2B) a_n2t scatter chunks; [2B, 6B) out1 col-chunks.
// ---------------------------------------------------------------------------
__global__ __launch_bounds__(256) void k_ant_o1(
    const float* __restrict__ n2t,
    const float* __restrict__ W1, const float* __restrict__ b1,
    float* __restrict__ out_ant)
{
    __shared__ float cat[1024];
    __shared__ float red[256];
    const int tid = threadIdx.x;
    int bid = blockIdx.x;

    if (bid < 2 * Bv) {
        // ---- a_n2t ----
        const int b = bid >> 1, ks = bid & 1;
        if (tid < NKv) red[tid] = g_ans[b * NKv + tid];
        __syncthreads();
        if (tid < 200) {
            const int t = ks * 200 + tid;
            const float* nb = n2t + (size_t)b * NKv * TKv + t;
            float at = 0.f;
            #pragma unroll
            for (int n = 0; n < NKv; n++) at += red[n] * nb[n * TKv];
            out_ant[b * TKv + t] = at * g_inv4[b];
        }
        return;
    }
    bid -= 2 * Bv;
    {
        // ---- out1 ----
        const int b = bid >> 2, cc = bid & 3;
        cat[tid]       = g_h  [b * 256 + tid];
        cat[256 + tid] = g_cd [b * 256 + tid];
        cat[512 + tid] = g_cg [b * 256 + tid];
        cat[768 + tid] = g_cg2[b * 256 + tid];
        __syncthreads();

        const int lane = tid & 63, kq = tid >> 6;
        const int col = cc * 64 + lane;
        const float* w  = W1 + (size_t)(kq * 256) * 256 + col;
        const float* cs = cat + kq * 256;
        float acc = 0.f;
        #pragma unroll 8
        for (int k = 0; k < 256; k++) acc += cs[k] * w[(size_t)k * 256];
        red[tid] = acc; __syncthreads();

        if (tid < 64) {
            float o = b1[cc * 64 + tid]
                    + red[tid] + red[64 + tid] + red[128 + tid] + red[192 + tid];
            g_o1[b * 256 + cc * 64 + tid] = o;
            g_o1b[b * 256 + cc * 64 + tid] = f2bf(o);
        }
    }
}

// ---------------------------------------------------------------------------
// K7 (MFMA): logits chunk + fused per-row (max, sumexp) partial.
// ---------------------------------------------------------------------------
__global__ __launch_bounds__(256) void k_logits(const float* __restrict__ b2)
{
    const int v0 = blockIdx.x * 64;
    const int tid = threadIdx.x;
    const int lane = tid & 63, wave = tid >> 6;
    const int nlow = lane & 15, quad = lane >> 4;

    const u16* a0p = g_o1b + (wave * 32 + nlow) * 256 + quad * 8;
    const u16* a1p = a0p + 16 * 256;
    const u16* bbase = g_W2t + (size_t)(v0 + nlow) * 256 + quad * 8;

    const f32x4 zf = {0.f, 0.f, 0.f, 0.f};
    f32x4 acc0[4], acc1[4];
    #pragma unroll
    for (int i = 0; i < 4; i++) { acc0[i] = zf; acc1[i] = zf; }

    for (int k0 = 0; k0 < 256; k0 += 32) {
        bf16x8 a0 = *(const bf16x8*)(a0p + k0);
        bf16x8 a1 = *(const bf16x8*)(a1p + k0);
        #pragma unroll
        for (int nt = 0; nt < 4; nt++) {
            bf16x8 bf = *(const bf16x8*)(bbase + (size_t)nt * 4096 + k0);
            acc0[nt] = __builtin_amdgcn_mfma_f32_16x16x32_bf16(a0, bf, acc0[nt], 0, 0, 0);
            acc1[nt] = __builtin_amdgcn_mfma_f32_16x16x32_bf16(a1, bf, acc1[nt], 0, 0, 0);
        }
    }

    float bbv[4]; bool val[4];
    #pragma unroll
    for (int nt = 0; nt < 4; nt++) {
        int v = v0 + nt * 16 + nlow;
        val[nt] = v < Vv;
        bbv[nt] = val[nt] ? b2[v] : 0.f;
    }

    #pragma unroll
    for (int mi = 0; mi < 2; mi++) {
        #pragma unroll
        for (int r = 0; r < 4; r++) {
            const int row = wave * 32 + mi * 16 + quad * 4 + r;
            float x[4];
            #pragma unroll
            for (int nt = 0; nt < 4; nt++) {
                float xv = (mi ? acc1[nt][r] : acc0[nt][r]) + bbv[nt];
                if (val[nt]) g_logits[(size_t)row * Vv + v0 + nt * 16 + nlow] = xv;
                x[nt] = val[nt] ? xv : -1e30f;
            }
            float m = fmaxf(fmaxf(x[0], x[1]), fmaxf(x[2], x[3]));
            m = fmaxf(m, __shfl_xor(m, 1, 64));
            m = fmaxf(m, __shfl_xor(m, 2, 64));
            m = fmaxf(m, __shfl_xor(m, 4, 64));
            m = fmaxf(m, __shfl_xor(m, 8, 64));
            float s = expf(x[0] - m) + expf(x[1] - m)
                    + expf(x[2] - m) + expf(x[3] - m);
            s += __shfl_xor(s, 1, 64);
            s += __shfl_xor(s, 2, 64);
            s += __shfl_xor(s, 4, 64);
            s += __shfl_xor(s, 8, 64);
            if (nlow == 0) {
                g_vpp[((size_t)row * NBLK + blockIdx.x) * 2]     = m;
                g_vpp[((size_t)row * NBLK + blockIdx.x) * 2 + 1] = s;
            }
        }
    }
}

// ---------------------------------------------------------------------------
// K8a: merge NBLK (max,sum) pairs (redundant per block, L2-hot), then write
// exp(x-M)*pg/S with float4 stores. grid (B, NS). NO fence, NO atomics.
// ---------------------------------------------------------------------------
__global__ __launch_bounds__(256) void k_vwrite(float* __restrict__ outF)
{
    const int b = blockIdx.x, ks = blockIdx.y, tid = threadIdx.x;
    __shared__ float rm[256], rs[256];

    float M = -1e30f, S = 0.f;
    for (int i = tid; i < NBLK; i += 256)
        ms_merge(M, S, g_vpp[((size_t)b * NBLK + i) * 2],
                       g_vpp[((size_t)b * NBLK + i) * 2 + 1]);
    rm[tid] = M; rs[tid] = S; __syncthreads();
    for (int off = 128; off > 0; off >>= 1) {
        if (tid < off) {
            float m1 = rm[tid], s1 = rs[tid];
            ms_merge(m1, s1, rm[tid + off], rs[tid + off]);
            rm[tid] = m1; rs[tid] = s1;
        }
        __syncthreads();
    }
    M = rm[0];
    const float inv = g_pg[b] / rs[0];

    const int base = ks * CHUNKv;
    const int end  = min(base + CHUNKv, Vv);
    const int n4   = (end - base) >> 2;
    const float4* L4 = (const float4*)(g_logits + (size_t)b * Vv + base);
    float4* O4 = (float4*)(outF + (size_t)b * Vv + base);

    for (int i = tid; i < n4; i += 256) {
        float4 x = L4[i];
        float4 r;
        r.x = expf(x.x - M) * inv;
        r.y = expf(x.y - M) * inv;
        r.z = expf(x.z - M) * inv;
        r.w = expf(x.w - M) * inv;
        O4[i] = r;
    }
}

// ---------------------------------------------------------------------------
// K8b: row-local pointer scatter (1-pg)*a[b,t] at voc_d[b,t]. Separate
// launch: stream order provides write->scatter ordering, atomics hit
// clean lines.
// ---------------------------------------------------------------------------
__global__ __launch_bounds__(256) void k_scatter(
    float* __restrict__ outF, const int* __restrict__ vocd)
{
    const int b = blockIdx.x, tid = threadIdx.x;
    float* Ob = outF + (size_t)b * Vv;
    const float omp = 1.f - g_pg[b];
    for (int t = tid; t < TKv; t += 256)
        atomicAdd(Ob + vocd[b * TKv + t], omp * g_a[b * TKv + t]);
}

// ---------------------------------------------------------------------------

extern "C" void kernel_launch(void* const* d_in, const int* in_sizes, int n_in,
                              void* d_out, int out_size, void* d_ws, size_t ws_size,
                              hipStream_t stream)
{
    (void)in_sizes; (void)n_in; (void)out_size; (void)d_ws; (void)ws_size;

    const int*   y      = (const int*)d_in[0];
    const float* h_prev = (const float*)d_in[1];
    const float* c_prev = (const float*)d_in[2];
    const float* enc    = (const float*)d_in[3];
    const float* encn   = (const float*)d_in[4];
    const float* mask   = (const float*)d_in[5];
    const float* maskn  = (const float*)d_in[6];
    const float* ctd    = (const float*)d_in[7];
    const float* ctg    = (const float*)d_in[8];
    const float* ctg2   = (const float*)d_in[9];
    const float* cov    = (const float*)d_in[10];
    const float* flow   = (const float*)d_in[11];
    const float* n2t    = (const float*)d_in[12];
    const float* graph  = (const float*)d_in[13];
    const int*   vocd   = (const int*)d_in[14];
    // d_in[15] = step (unused)
    const float* emb    = (const float*)d_in[16];
    const float* Wx     = (const float*)d_in[17];
    const float* bx     = (const float*)d_in[18];
    const float* Wi     = (const float*)d_in[19];
    const float* Wh     = (const float*)d_in[20];
    const float* bi     = (const float*)d_in[21];
    const float* bh     = (const float*)d_in[22];
    const float* Whd    = (const float*)d_in[23];
    const float* Wsd    = (const float*)d_in[24];
    const float* wcdw   = (const float*)d_in[25];
    const float* vd     = (const float*)d_in[26];
    const float* bd     = (const float*)d_in[27];
    const float* Wn     = (const float*)d_in[28];
    const float* Wsf    = (const float*)d_in[29];
    const float* vf     = (const float*)d_in[30];
    const float* bfv    = (const float*)d_in[31];
    const float* Wpg    = (const float*)d_in[32];
    const float* bpg    = (const float*)d_in[33];
    const float* W1     = (const float*)d_in[34];
    const float* b1     = (const float*)d_in[35];
    const float* W2     = (const float*)d_in[36];
    const float* b2     = (const float*)d_in[37];

    float* o = (float*)d_out;                 // FLOAT32 output
    float* o_final = o;                       // 6,400,000
    float* o_h     = o + 6400000;
    float* o_c     = o + 6432768;
    float* o_cd    = o + 6465536;
    float* o_cg    = o + 6498304;
    float* o_cg2   = o + 6531072;
    float* o_a     = o + 6563840;
    float* o_ant   = o + 6615040;
    float* o_pg    = o + 6666240;
    float* o_cov   = o + 6666368;
    float* o_fl    = o + 6717568;

    // 1. all input-only preprocessing (weight tc, enc cvt, x-partials)
    k_prep<<<dim3(NB_PREP), dim3(256), 0, stream>>>(
        Whd, Wn, W2, enc, encn, y, ctd, ctg, ctg2, emb, Wx);

    // 2-3. LSTM front-end chain
    k_gates<<<dim3(Bv, 4), dim3(256), 0, stream>>>(h_prev, Wi, Wh, bi, bh, bx);

    k_cellsd<<<dim3(Bv, 2), dim3(256), 0, stream>>>(c_prev, Wsd, Wsf, o_h, o_c);

    // 4. doc + node attention scores in one launch
    k_scores_all<<<dim3(MDOC / 128 + MNODE / 128, 4), dim3(256), 0, stream>>>(
        bd, bfv, cov, wcdw, vd, vf);

    // 5. doc softmax
    k_doc<<<dim3(Bv), dim3(256), 0, stream>>>(mask, cov, o_a, o_cov);

    // 6. flow-max/rowsum + c_d partials
    k_fmax_cd<<<dim3(Bv * NKv + Bv * 8), dim3(256), 0, stream>>>(n2t, enc);

    // 7. node chain + p_gen + flow normalize
    k_node1<<<dim3(Bv), dim3(256), 0, stream>>>(
        encn, maskn, flow, graph, Wpg, bpg,
        o_cd, o_cg, o_cg2, o_pg, o_fl);

    // 8. a_n2t + out1
    k_ant_o1<<<dim3(2 * Bv + 4 * Bv), dim3(256), 0, stream>>>(n2t, W1, b1, o_ant);

    // 9. logits + per-row (max,sum) partials
    k_logits<<<dim3(NBLK), dim3(256), 0, stream>>>(b2);

    // 10. softmax write (merge folded, no fence/atomics)
    k_vwrite<<<dim3(Bv, NSv), dim3(256), 0, stream>>>(o_final);

    // 11. pointer scatter (separate launch; stream order = ordering)
    k_scatter<<<dim3(Bv), dim3(256), 0, stream>>>(o_final, vocd);
}